// Round 1
// baseline (491.875 us; speedup 1.0000x reference)
//
#include <hip/hip_runtime.h>
#include <hip/hip_bf16.h>
#include <stdint.h>

#define M_DIM 8192
#define N_DIM 4096
#define K_DIM 4096
#define NNZ   1600000

typedef __attribute__((ext_vector_type(8))) short bf16x8;
typedef __attribute__((ext_vector_type(4))) float f32x4;

// workspace layout (bytes)
//   [0,               64MB)  W fp32 accumulator
//   [64MB,            96MB)  W bf16
//   [96MB,           160MB)  x bf16
static const size_t WF32_OFF  = 0;
static const size_t WBF16_OFF = 64ull << 20;
static const size_t XB_OFF    = 96ull << 20;
static const size_t WS_NEED   = 160ull << 20;

__device__ __forceinline__ unsigned short f2bf(float f) {
    union { float f; uint32_t u; } a; a.f = f;
    uint32_t u = a.u;
    uint32_t r = (u + 0x7FFFu + ((u >> 16) & 1u)) >> 16;   // round-to-nearest-even
    return (unsigned short)r;
}

__global__ void scatter_kernel(const int* __restrict__ idx,
                               const float* __restrict__ vals,
                               float* __restrict__ W) {
    int t = blockIdx.x * blockDim.x + threadIdx.x;
    if (t < NNZ) {
        int2 rc = ((const int2*)idx)[t];
        atomicAdd(&W[(size_t)rc.x * K_DIM + rc.y], vals[t]);
    }
}

// converts 4 fp32 -> 4 bf16 per thread
__global__ void f32_to_bf16_kernel(const float* __restrict__ src,
                                   unsigned short* __restrict__ dst, int n4) {
    int t = blockIdx.x * blockDim.x + threadIdx.x;
    if (t < n4) {
        float4 v = ((const float4*)src)[t];
        ushort4 o;
        o.x = f2bf(v.x); o.y = f2bf(v.y); o.z = f2bf(v.z); o.w = f2bf(v.w);
        ((ushort4*)dst)[t] = o;
    }
}

// ---------------------------------------------------------------------------
// bf16 MFMA GEMM: C[M,N] = relu(A[M,K] * B[N,K]^T), row-major, K contiguous.
// 128x128 tile, BK=64, 4 waves (2x2), each wave 64x64 via 4x4 16x16x32 frags.
// global_load_lds(16B) staging, pre-swizzled global source + XOR'd ds_read.
// ---------------------------------------------------------------------------
__global__ __launch_bounds__(256) void gemm_bf16_relu(
        const __hip_bfloat16* __restrict__ A,   // M x K
        const __hip_bfloat16* __restrict__ B,   // N x K
        float* __restrict__ C)                  // M x N
{
    __shared__ __align__(16) __hip_bfloat16 As[128 * 64];
    __shared__ __align__(16) __hip_bfloat16 Bs[128 * 64];

    const int tid  = threadIdx.x;
    const int lane = tid & 63;
    const int wid  = tid >> 6;

    // XCD-aware bijective swizzle (nwg = 2048, divisible by 8)
    const int bid = blockIdx.x;
    const int cpx = gridDim.x >> 3;
    const int swz = (bid & 7) * cpx + (bid >> 3);
    const int mt  = swz >> 5;        // 64 m-tiles
    const int nt  = swz & 31;        // 32 n-tiles
    const int m0  = mt * 128, n0 = nt * 128;

    const int wr = wid >> 1, wc = wid & 1;
    const int l15 = lane & 15, l4 = lane >> 4;

    f32x4 acc[4][4] = {};

    for (int kt = 0; kt < K_DIM; kt += 64) {
        // ---- stage A,B tiles (128 rows x 64 bf16 each) ----
        #pragma unroll
        for (int c = 0; c < 4; ++c) {
            const int sbase = c * 256 + wid * 64;       // wave-uniform slot base
            const int s = sbase + lane;                 // 16B-slot index [0,1024)
            const int r = s >> 3;                       // tile row
            const int u = s & 7;                        // 16B col-slot within row
            const int col8 = u ^ (r & 7);               // inverse-swizzled source
            const __hip_bfloat16* ga = A + (size_t)(m0 + r) * K_DIM + kt + col8 * 8;
            const __hip_bfloat16* gb = B + (size_t)(n0 + r) * K_DIM + kt + col8 * 8;
            __builtin_amdgcn_global_load_lds(
                (const __attribute__((address_space(1))) void*)ga,
                (__attribute__((address_space(3))) void*)(&As[sbase * 8]), 16, 0, 0);
            __builtin_amdgcn_global_load_lds(
                (const __attribute__((address_space(1))) void*)gb,
                (__attribute__((address_space(3))) void*)(&Bs[sbase * 8]), 16, 0, 0);
        }
        __syncthreads();

        // ---- compute: 2 x (8 ds_read_b128 + 16 MFMA) ----
        #pragma unroll
        for (int kk = 0; kk < 2; ++kk) {
            const int ks = kk * 4 + l4;                 // kslot 0..7
            bf16x8 a[4], b[4];
            #pragma unroll
            for (int m = 0; m < 4; ++m) {
                const int row = wr * 64 + m * 16 + l15;
                a[m] = *(const bf16x8*)(&As[row * 64 + ((ks ^ (row & 7)) << 3)]);
            }
            #pragma unroll
            for (int n = 0; n < 4; ++n) {
                const int row = wc * 64 + n * 16 + l15;
                b[n] = *(const bf16x8*)(&Bs[row * 64 + ((ks ^ (row & 7)) << 3)]);
            }
            #pragma unroll
            for (int m = 0; m < 4; ++m)
                #pragma unroll
                for (int n = 0; n < 4; ++n)
                    acc[m][n] = __builtin_amdgcn_mfma_f32_16x16x32_bf16(
                                    a[m], b[n], acc[m][n], 0, 0, 0);
        }
        __syncthreads();
    }

    // ---- epilogue: ReLU + store fp32 ----
    #pragma unroll
    for (int m = 0; m < 4; ++m) {
        #pragma unroll
        for (int n = 0; n < 4; ++n) {
            #pragma unroll
            for (int j = 0; j < 4; ++j) {
                const int row = m0 + wr * 64 + m * 16 + l4 * 4 + j;
                const int col = n0 + wc * 64 + n * 16 + l15;
                C[(size_t)row * N_DIM + col] = fmaxf(acc[m][n][j], 0.0f);
            }
        }
    }
}

// ---------------------------------------------------------------------------
// fp32 fallback GEMM (only if ws_size < 160MB): 64x64 tile, correct but slow.
// ---------------------------------------------------------------------------
__global__ void gemm_f32_fallback(const float* __restrict__ A,
                                  const float* __restrict__ W,
                                  float* __restrict__ C) {
    __shared__ float As[64][17];
    __shared__ float Bs[64][17];
    const int tx = threadIdx.x & 15, ty = threadIdx.x >> 4;
    const int m0 = blockIdx.y * 64, n0 = blockIdx.x * 64;
    float acc[4][4] = {};
    for (int kt = 0; kt < K_DIM; kt += 16) {
        #pragma unroll
        for (int i = 0; i < 4; ++i) {
            int e = threadIdx.x + i * 256;
            int r = e >> 4, k = e & 15;
            As[r][k] = A[(size_t)(m0 + r) * K_DIM + kt + k];
            Bs[r][k] = W[(size_t)(n0 + r) * K_DIM + kt + k];
        }
        __syncthreads();
        #pragma unroll
        for (int k = 0; k < 16; ++k) {
            float av[4], bv[4];
            #pragma unroll
            for (int i = 0; i < 4; ++i) av[i] = As[ty * 4 + i][k];
            #pragma unroll
            for (int i = 0; i < 4; ++i) bv[i] = Bs[tx * 4 + i][k];
            #pragma unroll
            for (int i = 0; i < 4; ++i)
                #pragma unroll
                for (int j = 0; j < 4; ++j) acc[i][j] += av[i] * bv[j];
        }
        __syncthreads();
    }
    #pragma unroll
    for (int i = 0; i < 4; ++i)
        #pragma unroll
        for (int j = 0; j < 4; ++j)
            C[(size_t)(m0 + ty * 4 + i) * N_DIM + n0 + tx * 4 + j] =
                fmaxf(acc[i][j], 0.0f);
}

extern "C" void kernel_launch(void* const* d_in, const int* in_sizes, int n_in,
                              void* d_out, int out_size, void* d_ws, size_t ws_size,
                              hipStream_t stream) {
    const float* x       = (const float*)d_in[0];
    const int*   indices = (const int*)d_in[1];
    const float* values  = (const float*)d_in[2];
    float*       out     = (float*)d_out;

    float* Wf = (float*)((char*)d_ws + WF32_OFF);

    // 1. zero + scatter-build W (fp32, duplicates accumulate)
    hipMemsetAsync(Wf, 0, (size_t)N_DIM * K_DIM * sizeof(float), stream);
    scatter_kernel<<<(NNZ + 255) / 256, 256, 0, stream>>>(indices, values, Wf);

    if (ws_size >= WS_NEED) {
        unsigned short* Wb = (unsigned short*)((char*)d_ws + WBF16_OFF);
        unsigned short* xb = (unsigned short*)((char*)d_ws + XB_OFF);

        // 2. fp32 -> bf16 conversions
        {
            int n4 = (N_DIM * K_DIM) / 4;
            f32_to_bf16_kernel<<<(n4 + 255) / 256, 256, 0, stream>>>(Wf, Wb, n4);
        }
        {
            int n4 = (M_DIM * K_DIM) / 4;
            f32_to_bf16_kernel<<<(n4 + 255) / 256, 256, 0, stream>>>(x, xb, n4);
        }

        // 3. bf16 MFMA GEMM + ReLU
        gemm_bf16_relu<<<(M_DIM / 128) * (N_DIM / 128), 256, 0, stream>>>(
            (const __hip_bfloat16*)xb, (const __hip_bfloat16*)Wb, out);
    } else {
        gemm_f32_fallback<<<dim3(N_DIM / 64, M_DIM / 64), 256, 0, stream>>>(
            x, Wf, out);
    }
}

// Round 2
// 417.022 us; speedup vs baseline: 1.1795x; 1.1795x over previous
//
#include <hip/hip_runtime.h>
#include <hip/hip_bf16.h>
#include <stdint.h>

#define M_DIM 8192
#define N_DIM 4096
#define K_DIM 4096
#define NNZ   1600000

typedef __attribute__((ext_vector_type(8))) short bf16x8;
typedef __attribute__((ext_vector_type(4))) float f32x4;

// workspace layout (bytes)
//   [0,               64MB)  W fp32 accumulator
//   [64MB,            96MB)  W bf16
//   [96MB,           160MB)  x bf16
static const size_t WF32_OFF  = 0;
static const size_t WBF16_OFF = 64ull << 20;
static const size_t XB_OFF    = 96ull << 20;
static const size_t WS_NEED   = 160ull << 20;

__device__ __forceinline__ unsigned short f2bf(float f) {
    union { float f; uint32_t u; } a; a.f = f;
    uint32_t u = a.u;
    uint32_t r = (u + 0x7FFFu + ((u >> 16) & 1u)) >> 16;   // round-to-nearest-even
    return (unsigned short)r;
}

__global__ void scatter_kernel(const int* __restrict__ idx,
                               const float* __restrict__ vals,
                               float* __restrict__ W) {
    int t = blockIdx.x * blockDim.x + threadIdx.x;
    if (t < NNZ) {
        int2 rc = ((const int2*)idx)[t];
        atomicAdd(&W[(size_t)rc.x * K_DIM + rc.y], vals[t]);
    }
}

__global__ void f32_to_bf16_kernel(const float* __restrict__ src,
                                   unsigned short* __restrict__ dst, int n4) {
    int t = blockIdx.x * blockDim.x + threadIdx.x;
    if (t < n4) {
        float4 v = ((const float4*)src)[t];
        ushort4 o;
        o.x = f2bf(v.x); o.y = f2bf(v.y); o.z = f2bf(v.z); o.w = f2bf(v.w);
        ((ushort4*)dst)[t] = o;
    }
}

// ---------------------------------------------------------------------------
// 256x256 8-phase bf16 MFMA GEMM: C = relu(A[M,K] * B[N,K]^T)
// 8 waves (2M x 4N), BK=64, double-buffered 128KB LDS, counted vmcnt,
// per-phase {ds_read || gload_lds -> bar -> lgkm0 -> setprio+16 MFMA -> bar}.
// LDS swizzle: 16B slot u at row r stored at u^(r&7); inverse-swizzled global
// source keeps gload_lds dest linear (rule 21).
// ---------------------------------------------------------------------------
#define GLOAD16(gp, lp) __builtin_amdgcn_global_load_lds( \
    (const __attribute__((address_space(1))) void*)(gp),  \
    (__attribute__((address_space(3))) void*)(lp), 16, 0, 0)
#define VMCNT(n)   asm volatile("s_waitcnt vmcnt(" #n ")" ::: "memory")
#define LGKMCNT(n) asm volatile("s_waitcnt lgkmcnt(" #n ")" ::: "memory")
#define BAR() __builtin_amdgcn_s_barrier()
#define SCHED0() __builtin_amdgcn_sched_barrier(0)

// read bf16x8 frag: tile T (256x64 bf16, swizzled), row r, k-slot kk (0/1)
#define FRAG(T, r, kk) \
    (*(const bf16x8*)&(T)[(r)*64 + (((((kk)<<2) + l4) ^ ((r)&7)) << 3)])

// stage half h (128 rows) of one 256x64 tile: 2 gload_lds x 512 threads x 16B
#define STAGE_A(buf, kt, h) do {                                              \
    GLOAD16(Ab + (size_t)((h)*128 + rl0) * K_DIM + (kt) + cs0,                \
            &sA[buf][(h)*8192 + wid*512]);                                    \
    GLOAD16(Ab + (size_t)((h)*128 + rl1) * K_DIM + (kt) + cs1,                \
            &sA[buf][(h)*8192 + 4096 + wid*512]);                             \
  } while (0)
#define STAGE_B(buf, kt, h) do {                                              \
    GLOAD16(Bb + (size_t)((h)*128 + rl0) * K_DIM + (kt) + cs0,                \
            &sB[buf][(h)*8192 + wid*512]);                                    \
    GLOAD16(Bb + (size_t)((h)*128 + rl1) * K_DIM + (kt) + cs1,                \
            &sB[buf][(h)*8192 + 4096 + wid*512]);                             \
  } while (0)

__global__ __launch_bounds__(512, 2) void gemm256_8ph(
        const __hip_bfloat16* __restrict__ A,   // M x K
        const __hip_bfloat16* __restrict__ B,   // N x K
        float* __restrict__ C)                  // M x N
{
    __shared__ __align__(16) __hip_bfloat16 sA[2][256 * 64];
    __shared__ __align__(16) __hip_bfloat16 sB[2][256 * 64];

    const int tid  = threadIdx.x;
    const int lane = tid & 63;
    const int wid  = tid >> 6;
    const int wr   = wid >> 2;      // 0..1  (128-row half)
    const int wc   = wid & 3;       // 0..3  (64-col slice)
    const int l15  = lane & 15, l4 = lane >> 4;

    // XCD-aware bijective swizzle (nwg = 512, divisible by 8)
    const int bid = blockIdx.x;
    const int swz = (bid & 7) * 64 + (bid >> 3);
    const int m0  = (swz >> 4) * 256;   // 32 m-tiles
    const int n0  = (swz & 15) * 256;   // 16 n-tiles

    // staging geometry: slot s = i*512 + tid over a 128-row half (1024 slots)
    const int s0 = tid, s1 = 512 + tid;
    const int rl0 = s0 >> 3, cs0 = ((s0 & 7) ^ (rl0 & 7)) << 3;
    const int rl1 = s1 >> 3, cs1 = ((s1 & 7) ^ (rl1 & 7)) << 3;
    const __hip_bfloat16* Ab = A + (size_t)m0 * K_DIM;
    const __hip_bfloat16* Bb = B + (size_t)n0 * K_DIM;

    f32x4  acc[8][4] = {};
    bf16x8 aLo[4][2], aHi[4][2], bLo[2][2], bHi[2][2];

    // ---- prologue: tile0 (all 4 halves) + tile1 A-halves; keep A(1) in flight
    STAGE_A(0, 0, 0);  STAGE_A(0, 0, 1);
    STAGE_B(0, 0, 0);  STAGE_B(0, 0, 1);
    STAGE_A(1, 64, 0); STAGE_A(1, 64, 1);
    VMCNT(4);
    BAR();

    for (int t = 0; t < 64; ++t) {
        const int c = t & 1;
        const __hip_bfloat16* TA = sA[c];
        const __hip_bfloat16* TB = sB[c];
        const int ktn = (t + 1) << 6;

        // ---- phase 0: quad (mq=0, nq=0) ----
        #pragma unroll
        for (int m = 0; m < 4; ++m) {
            const int r = wr * 128 + m * 16 + l15;
            aLo[m][0] = FRAG(TA, r, 0);
            aLo[m][1] = FRAG(TA, r, 1);
        }
        #pragma unroll
        for (int n = 0; n < 2; ++n) {
            const int r = wc * 64 + n * 16 + l15;
            bLo[n][0] = FRAG(TB, r, 0);
            bLo[n][1] = FRAG(TB, r, 1);
        }
        if (t < 63) STAGE_B(c ^ 1, ktn, 0);
        LGKMCNT(8);
        BAR();
        LGKMCNT(0); SCHED0();
        __builtin_amdgcn_s_setprio(1);
        #pragma unroll
        for (int k = 0; k < 2; ++k)
            #pragma unroll
            for (int m = 0; m < 4; ++m)
                #pragma unroll
                for (int n = 0; n < 2; ++n)
                    acc[m][n] = __builtin_amdgcn_mfma_f32_16x16x32_bf16(
                                    aLo[m][k], bLo[n][k], acc[m][n], 0, 0, 0);
        __builtin_amdgcn_s_setprio(0);
        BAR();

        // ---- phase 1: quad (mq=1, nq=0) ----
        #pragma unroll
        for (int m = 0; m < 4; ++m) {
            const int r = wr * 128 + 64 + m * 16 + l15;
            aHi[m][0] = FRAG(TA, r, 0);
            aHi[m][1] = FRAG(TA, r, 1);
        }
        if (t < 63) STAGE_B(c ^ 1, ktn, 1);
        BAR();
        LGKMCNT(0); SCHED0();
        __builtin_amdgcn_s_setprio(1);
        #pragma unroll
        for (int k = 0; k < 2; ++k)
            #pragma unroll
            for (int m = 0; m < 4; ++m)
                #pragma unroll
                for (int n = 0; n < 2; ++n)
                    acc[4 + m][n] = __builtin_amdgcn_mfma_f32_16x16x32_bf16(
                                    aHi[m][k], bLo[n][k], acc[4 + m][n], 0, 0, 0);
        __builtin_amdgcn_s_setprio(0);
        BAR();

        // ---- phase 2: quad (mq=1, nq=1) ----
        #pragma unroll
        for (int n = 0; n < 2; ++n) {
            const int r = wc * 64 + 32 + n * 16 + l15;
            bHi[n][0] = FRAG(TB, r, 0);
            bHi[n][1] = FRAG(TB, r, 1);
        }
        BAR();
        LGKMCNT(0); SCHED0();
        __builtin_amdgcn_s_setprio(1);
        #pragma unroll
        for (int k = 0; k < 2; ++k)
            #pragma unroll
            for (int m = 0; m < 4; ++m)
                #pragma unroll
                for (int n = 0; n < 2; ++n)
                    acc[4 + m][2 + n] = __builtin_amdgcn_mfma_f32_16x16x32_bf16(
                                    aHi[m][k], bHi[n][k], acc[4 + m][2 + n], 0, 0, 0);
        __builtin_amdgcn_s_setprio(0);
        BAR();
        // after this barrier no wave reads buf c again this tile -> safe to
        // overwrite buf c with tile t+2 during/after phase 3.

        // ---- phase 3: quad (mq=0, nq=1), registers only ----
        __builtin_amdgcn_s_setprio(1);
        #pragma unroll
        for (int k = 0; k < 2; ++k)
            #pragma unroll
            for (int m = 0; m < 4; ++m)
                #pragma unroll
                for (int n = 0; n < 2; ++n)
                    acc[m][2 + n] = __builtin_amdgcn_mfma_f32_16x16x32_bf16(
                                    aLo[m][k], bHi[n][k], acc[m][2 + n], 0, 0, 0);
        __builtin_amdgcn_s_setprio(0);

        // ---- boundary: issue A(t+2) into buf c, counted wait (never 0) ----
        if (t < 62) {
            STAGE_A(c, ktn + 64, 0);
            STAGE_A(c, ktn + 64, 1);
            VMCNT(4);           // drains all of tile t+1; A(t+2) stays in flight
            BAR();
        } else if (t == 62) {
            VMCNT(0);           // tail: drain B(63)
            BAR();
        }
    }

    // ---- epilogue: ReLU + fp32 store ----
    const int row_base = m0 + wr * 128;
    const int col_base = n0 + wc * 64;
    #pragma unroll
    for (int mq = 0; mq < 2; ++mq)
        #pragma unroll
        for (int m = 0; m < 4; ++m)
            #pragma unroll
            for (int nq = 0; nq < 2; ++nq)
                #pragma unroll
                for (int n = 0; n < 2; ++n) {
                    const f32x4 v = acc[mq * 4 + m][nq * 2 + n];
                    const int col = col_base + nq * 32 + n * 16 + l15;
                    #pragma unroll
                    for (int j = 0; j < 4; ++j) {
                        const int row = row_base + mq * 64 + m * 16 + l4 * 4 + j;
                        C[(size_t)row * N_DIM + col] = fmaxf(v[j], 0.0f);
                    }
                }
}

// ---------------------------------------------------------------------------
// fp32 fallback GEMM (only if ws_size < 160MB)
// ---------------------------------------------------------------------------
__global__ void gemm_f32_fallback(const float* __restrict__ A,
                                  const float* __restrict__ W,
                                  float* __restrict__ C) {
    __shared__ float As[64][17];
    __shared__ float Bs[64][17];
    const int tx = threadIdx.x & 15, ty = threadIdx.x >> 4;
    const int m0 = blockIdx.y * 64, n0 = blockIdx.x * 64;
    float acc[4][4] = {};
    for (int kt = 0; kt < K_DIM; kt += 16) {
        #pragma unroll
        for (int i = 0; i < 4; ++i) {
            int e = threadIdx.x + i * 256;
            int r = e >> 4, k = e & 15;
            As[r][k] = A[(size_t)(m0 + r) * K_DIM + kt + k];
            Bs[r][k] = W[(size_t)(n0 + r) * K_DIM + kt + k];
        }
        __syncthreads();
        #pragma unroll
        for (int k = 0; k < 16; ++k) {
            float av[4], bv[4];
            #pragma unroll
            for (int i = 0; i < 4; ++i) av[i] = As[ty * 4 + i][k];
            #pragma unroll
            for (int i = 0; i < 4; ++i) bv[i] = Bs[tx * 4 + i][k];
            #pragma unroll
            for (int i = 0; i < 4; ++i)
                #pragma unroll
                for (int j = 0; j < 4; ++j) acc[i][j] += av[i] * bv[j];
        }
        __syncthreads();
    }
    #pragma unroll
    for (int i = 0; i < 4; ++i)
        #pragma unroll
        for (int j = 0; j < 4; ++j)
            C[(size_t)(m0 + ty * 4 + i) * N_DIM + n0 + tx * 4 + j] =
                fmaxf(acc[i][j], 0.0f);
}

extern "C" void kernel_launch(void* const* d_in, const int* in_sizes, int n_in,
                              void* d_out, int out_size, void* d_ws, size_t ws_size,
                              hipStream_t stream) {
    const float* x       = (const float*)d_in[0];
    const int*   indices = (const int*)d_in[1];
    const float* values  = (const float*)d_in[2];
    float*       out     = (float*)d_out;

    float* Wf = (float*)((char*)d_ws + WF32_OFF);

    // 1. zero + scatter-build W (fp32, duplicates accumulate)
    hipMemsetAsync(Wf, 0, (size_t)N_DIM * K_DIM * sizeof(float), stream);
    scatter_kernel<<<(NNZ + 255) / 256, 256, 0, stream>>>(indices, values, Wf);

    if (ws_size >= WS_NEED) {
        unsigned short* Wb = (unsigned short*)((char*)d_ws + WBF16_OFF);
        unsigned short* xb = (unsigned short*)((char*)d_ws + XB_OFF);

        // 2. fp32 -> bf16 conversions
        {
            int n4 = (N_DIM * K_DIM) / 4;
            f32_to_bf16_kernel<<<(n4 + 255) / 256, 256, 0, stream>>>(Wf, Wb, n4);
        }
        {
            int n4 = (M_DIM * K_DIM) / 4;
            f32_to_bf16_kernel<<<(n4 + 255) / 256, 256, 0, stream>>>(x, xb, n4);
        }

        // 3. 256^2 8-phase bf16 MFMA GEMM + ReLU
        gemm256_8ph<<<(M_DIM / 256) * (N_DIM / 256), 512, 0, stream>>>(
            (const __hip_bfloat16*)xb, (const __hip_bfloat16*)Wb, out);
    } else {
        gemm_f32_fallback<<<dim3(N_DIM / 64, M_DIM / 64), 256, 0, stream>>>(
            x, Wf, out);
    }
}